// Round 1
// baseline (122.311 us; speedup 1.0000x reference)
//
#include <hip/hip_runtime.h>
#include <hip/hip_bf16.h>

#define DEVI __device__ __forceinline__

typedef __attribute__((ext_vector_type(8))) short s16x8;
typedef __attribute__((ext_vector_type(4))) short s16x4;
typedef __attribute__((ext_vector_type(4))) float f32x4;

// ---- problem constants ----
// x: (8, 384, 32, 32); heads=8, dk=32, dv=64; N=1024 tokens; Cqk=256, Cv=512
// concat QKV channels: [0,256)=Q, [256,512)=K, [512,1024)=V

DEVI short f2bs(float f) {  // fp32 -> bf16 bits (RNE)
    unsigned u = __builtin_bit_cast(unsigned, f);
    unsigned r = (u + 0x7fffu + ((u >> 16) & 1u)) >> 16;
    return (short)r;
}

DEVI f32x4 mfma16(s16x8 a, s16x8 b, f32x4 c) {
    return __builtin_amdgcn_mfma_f32_16x16x32_bf16(a, b, c, 0, 0, 0);
}

// ---------------- prep: x (b,c,n) fp32 -> xt (b,n,c) bf16 ----------------
__global__ __launch_bounds__(256) void k_prep_x(const float* __restrict__ x,
                                                short* __restrict__ xt) {
    __shared__ float tile[32][33];
    const int ct = blockIdx.x, nt = blockIdx.y, b = blockIdx.z;
    const int t = threadIdx.x;
    {
        const int j = t & 31, i0 = (t >> 5) * 4;
        const float* src = x + ((size_t)b * 384 + (size_t)ct * 32) * 1024 + nt * 32;
#pragma unroll
        for (int ii = 0; ii < 4; ++ii)
            tile[i0 + ii][j] = src[(size_t)(i0 + ii) * 1024 + j];
    }
    __syncthreads();
    {
        const int ii = t & 31, j0 = (t >> 5) * 4;
        short* dst = xt + ((size_t)b * 1024 + (size_t)nt * 32) * 384 + ct * 32;
#pragma unroll
        for (int jj = 0; jj < 4; ++jj)
            dst[(size_t)(j0 + jj) * 384 + ii] = f2bs(tile[ii][j0 + jj]);
    }
}

// ---------------- prep: weights fp32 -> bf16 (wqkv concat + wproj) ----------------
__global__ __launch_bounds__(256) void k_prep_w(const float* __restrict__ wq,
                                                const float* __restrict__ wk,
                                                const float* __restrict__ wv,
                                                const float* __restrict__ wp,
                                                short* __restrict__ wqkv,
                                                short* __restrict__ wpb) {
    int i = blockIdx.x * 256 + threadIdx.x;
    const int NQKV = 1024 * 384;
    if (i < NQKV) {
        int o = i / 384;
        float v;
        if (o < 256)      v = wq[i];
        else if (o < 512) v = wk[i - 256 * 384];
        else              v = wv[i - 512 * 384];
        wqkv[i] = f2bs(v);
    } else {
        int j = i - NQKV;
        if (j < 384 * 512) wpb[j] = f2bs(wp[j]);
    }
}

// ---------------- prep: BN fold ----------------
__global__ __launch_bounds__(256) void k_prep_bn(
    const float* gq, const float* bq, const float* mq, const float* vq,
    const float* gk, const float* bk, const float* mk, const float* vk,
    const float* gv, const float* bv, const float* mv, const float* vv,
    const float* gp, const float* bp, const float* mp, const float* vp,
    float* s_qkv, float* t_qkv, float* s_p, float* t_p) {
    int i = blockIdx.x * 256 + threadIdx.x;
    if (i < 1024) {
        const float *g, *bb, *mm, *vv_;
        int o = i;
        if (i < 256)      { g = gq; bb = bq; mm = mq; vv_ = vq; }
        else if (i < 512) { g = gk; bb = bk; mm = mk; vv_ = vk; o = i - 256; }
        else              { g = gv; bb = bv; mm = mv; vv_ = vv; o = i - 512; }
        float s = g[o] * rsqrtf(vv_[o] + 1e-5f);
        s_qkv[i] = s;
        t_qkv[i] = bb[o] - mm[o] * s;
    }
    if (i < 384) {
        float s = gp[i] * rsqrtf(vp[i] + 1e-5f);
        s_p[i] = s;
        t_p[i] = bp[i] - mp[i] * s;
    }
}

// ---------------- QKV GEMM: [1024ch x 384] x [384 x 8192] + BN, layout-split ----------------
// Qw: [b][h][n][32]  Kw: [b][h][m][32]  Vw: [b][h][e][1024]
__global__ __launch_bounds__(256) void k_gemm_qkv(
    const short* __restrict__ wqkv, const short* __restrict__ xt,
    const float* __restrict__ s_qkv, const float* __restrict__ t_qkv,
    short* __restrict__ Qw, short* __restrict__ Kw, short* __restrict__ Vw) {
    const int t = threadIdx.x, lane = t & 63, w = t >> 6;
    const int g = lane >> 4, l15 = lane & 15;
    const int mb = blockIdx.x, jb = blockIdx.y;
    const int m_base = mb * 128 + (w >> 1) * 64;
    const int j_base = jb * 128 + (w & 1) * 64;

    f32x4 acc[4][4];
#pragma unroll
    for (int mi = 0; mi < 4; ++mi)
#pragma unroll
        for (int ni = 0; ni < 4; ++ni) acc[mi][ni] = f32x4{0.f, 0.f, 0.f, 0.f};

    const short* Arow = wqkv + (size_t)(m_base + l15) * 384 + 8 * g;
    const short* Brow = xt + (size_t)(j_base + l15) * 384 + 8 * g;

    for (int ks = 0; ks < 12; ++ks) {
        s16x8 a[4], b[4];
#pragma unroll
        for (int i = 0; i < 4; ++i)
            a[i] = *(const s16x8*)(Arow + (size_t)i * 16 * 384 + ks * 32);
#pragma unroll
        for (int i = 0; i < 4; ++i)
            b[i] = *(const s16x8*)(Brow + (size_t)i * 16 * 384 + ks * 32);
#pragma unroll
        for (int mi = 0; mi < 4; ++mi)
#pragma unroll
            for (int ni = 0; ni < 4; ++ni)
                acc[mi][ni] = mfma16(a[mi], b[ni], acc[mi][ni]);
    }

#pragma unroll
    for (int mi = 0; mi < 4; ++mi) {
        const int o0 = m_base + 16 * mi;
#pragma unroll
        for (int ni = 0; ni < 4; ++ni) {
            const int j = j_base + 16 * ni + l15;
            const int bb = j >> 10, n = j & 1023;
#pragma unroll
            for (int r = 0; r < 4; ++r) {
                const int o = o0 + 4 * g + r;
                float val = acc[mi][ni][r] * s_qkv[o] + t_qkv[o];
                short bv = f2bs(val);
                if (o0 < 256) {
                    int h = o >> 5, d = o & 31;
                    Qw[(((size_t)bb * 8 + h) * 1024 + n) * 32 + d] = bv;
                } else if (o0 < 512) {
                    int o2 = o - 256;
                    int h = o2 >> 5, d = o2 & 31;
                    Kw[(((size_t)bb * 8 + h) * 1024 + n) * 32 + d] = bv;
                } else {
                    int o2 = o - 512;
                    int h = o2 >> 6, e = o2 & 63;
                    Vw[(((size_t)bb * 8 + h) * 64 + e) * 1024 + n] = bv;
                }
            }
        }
    }
}

// ---------------- attention per (b,h): flash-online, S^T = mfma(K, Q) ----------------
// Ow: [b][n][512] bf16, ReLU applied
__global__ __launch_bounds__(256) void k_attn(const short* __restrict__ Qw,
                                              const short* __restrict__ Kw,
                                              const short* __restrict__ Vw,
                                              short* __restrict__ Ow) {
    __shared__ short Plds[4][4096];  // per-wave 64x64 bf16, XOR-swizzled
    __shared__ float Srow[4][64];
    __shared__ float Lrow[4][64];
    const int t = threadIdx.x, lane = t & 63, w = t >> 6;
    const int g = lane >> 4, l15 = lane & 15;
    const int bh = blockIdx.x >> 2, rb = blockIdx.x & 3;
    const int n_base = rb * 256 + w * 64;
    const short* Qb = Qw + (size_t)bh * (1024 * 32);
    const short* Kb = Kw + (size_t)bh * (1024 * 32);
    const short* Vb = Vw + (size_t)bh * (64 * 1024);
    short* Pl = Plds[w];
    float* Sr = Srow[w];
    float* Lr = Lrow[w];

    s16x8 qf[4];
#pragma unroll
    for (int i = 0; i < 4; ++i)
        qf[i] = *(const s16x8*)(Qb + (size_t)(n_base + 16 * i + l15) * 32 + 8 * g);

    f32x4 oacc[4][4];
#pragma unroll
    for (int mi = 0; mi < 4; ++mi)
#pragma unroll
        for (int ei = 0; ei < 4; ++ei) oacc[mi][ei] = f32x4{0.f, 0.f, 0.f, 0.f};
    float m_run[4], l_run[4];
#pragma unroll
    for (int i = 0; i < 4; ++i) { m_run[i] = -3e38f; l_run[i] = 0.f; }

    for (int mt = 0; mt < 16; ++mt) {
        const int m0 = mt * 64;
        s16x8 kf[4];
#pragma unroll
        for (int i = 0; i < 4; ++i)
            kf[i] = *(const s16x8*)(Kb + (size_t)(m0 + 16 * i + l15) * 32 + 8 * g);

        f32x4 st[4][4];  // S^T: row m = m0+16*mik+4g+r, col n = n_base+16*niq+l15
#pragma unroll
        for (int mik = 0; mik < 4; ++mik)
#pragma unroll
            for (int niq = 0; niq < 4; ++niq)
                st[mik][niq] = mfma16(kf[mik], qf[niq], f32x4{0.f, 0.f, 0.f, 0.f});

        // per-column-n (softmax-row) stats: reduce over regs + lane-groups
        float mnew[4], sc[4];
#pragma unroll
        for (int niq = 0; niq < 4; ++niq) {
            float v = st[0][niq][0];
#pragma unroll
            for (int mik = 0; mik < 4; ++mik)
#pragma unroll
                for (int r = 0; r < 4; ++r) v = fmaxf(v, st[mik][niq][r]);
            v = fmaxf(v, __shfl_xor(v, 16, 64));
            v = fmaxf(v, __shfl_xor(v, 32, 64));
            mnew[niq] = fmaxf(m_run[niq], v);
            sc[niq] = __expf(m_run[niq] - mnew[niq]);
            m_run[niq] = mnew[niq];
        }
        float psum[4] = {0.f, 0.f, 0.f, 0.f};
#pragma unroll
        for (int mik = 0; mik < 4; ++mik)
#pragma unroll
            for (int niq = 0; niq < 4; ++niq)
#pragma unroll
                for (int r = 0; r < 4; ++r) {
                    float p = __expf(st[mik][niq][r] - mnew[niq]);
                    st[mik][niq][r] = p;
                    psum[niq] += p;
                }
#pragma unroll
        for (int niq = 0; niq < 4; ++niq) {
            float s = psum[niq];
            s += __shfl_xor(s, 16, 64);
            s += __shfl_xor(s, 32, 64);
            l_run[niq] = l_run[niq] * sc[niq] + s;
        }
        if (g == 0) {
#pragma unroll
            for (int niq = 0; niq < 4; ++niq) Sr[16 * niq + l15] = sc[niq];
        }
        // P (bf16) -> LDS, layout P[n_local][m_local], byte ^= (n&7)<<4
#pragma unroll
        for (int mik = 0; mik < 4; ++mik)
#pragma unroll
            for (int niq = 0; niq < 4; ++niq) {
                s16x4 pk;
#pragma unroll
                for (int r = 0; r < 4; ++r) pk[r] = f2bs(st[mik][niq][r]);
                const int nr = 16 * niq + l15;
                const int off = (nr * 128 + 32 * mik + 8 * g) ^ ((nr & 7) << 4);
                *(s16x4*)((char*)Pl + off) = pk;
            }
        // rescale O by sc of its rows (rows n = 16*mi + 4g + r here)
        {
            float sco[4][4];
#pragma unroll
            for (int mi = 0; mi < 4; ++mi)
#pragma unroll
                for (int r = 0; r < 4; ++r) sco[mi][r] = Sr[16 * mi + 4 * g + r];
#pragma unroll
            for (int mi = 0; mi < 4; ++mi)
#pragma unroll
                for (int ei = 0; ei < 4; ++ei)
#pragma unroll
                    for (int r = 0; r < 4; ++r) oacc[mi][ei][r] *= sco[mi][r];
        }
        // PV: out[n][e] += P[n][m] * V[m][e]
#pragma unroll
        for (int ki = 0; ki < 2; ++ki) {
            s16x8 pa[4];
#pragma unroll
            for (int mi = 0; mi < 4; ++mi) {
                const int nr = 16 * mi + l15;
                const int off = (nr * 128 + 64 * ki + 16 * g) ^ ((nr & 7) << 4);
                pa[mi] = *(const s16x8*)((char*)Pl + off);
            }
            s16x8 vb[4];
#pragma unroll
            for (int ei = 0; ei < 4; ++ei)
                vb[ei] = *(const s16x8*)(Vb + (size_t)(16 * ei + l15) * 1024 + m0 + 32 * ki + 8 * g);
#pragma unroll
            for (int mi = 0; mi < 4; ++mi)
#pragma unroll
                for (int ei = 0; ei < 4; ++ei)
                    oacc[mi][ei] = mfma16(pa[mi], vb[ei], oacc[mi][ei]);
        }
    }

    if (g == 0) {
#pragma unroll
        for (int niq = 0; niq < 4; ++niq) Lr[16 * niq + l15] = l_run[niq];
    }
    const int b = bh >> 3, h = bh & 7;
#pragma unroll
    for (int mi = 0; mi < 4; ++mi) {
        float li[4];
#pragma unroll
        for (int r = 0; r < 4; ++r) li[r] = 1.0f / Lr[16 * mi + 4 * g + r];
#pragma unroll
        for (int ei = 0; ei < 4; ++ei) {
            const int e = 16 * ei + l15;
#pragma unroll
            for (int r = 0; r < 4; ++r) {
                const int n = n_base + 16 * mi + 4 * g + r;
                float v = fmaxf(oacc[mi][ei][r] * li[r], 0.f);
                Ow[((size_t)b * 1024 + n) * 512 + h * 64 + e] = f2bs(v);
            }
        }
    }
}

// ---------------- proj GEMM: [384 x 512] x [512 x 8192] + BN -> fp32 out ----------------
__global__ __launch_bounds__(256) void k_proj(const short* __restrict__ wpb,
                                              const short* __restrict__ Ow,
                                              const float* __restrict__ s_p,
                                              const float* __restrict__ t_p,
                                              float* __restrict__ out) {
    const int t = threadIdx.x, lane = t & 63, w = t >> 6;
    const int g = lane >> 4, l15 = lane & 15;
    const int mb = blockIdx.x, jb = blockIdx.y;
    const int m_base = mb * 128 + (w >> 1) * 64;
    const int j_base = jb * 128 + (w & 1) * 64;

    f32x4 acc[4][4];
#pragma unroll
    for (int mi = 0; mi < 4; ++mi)
#pragma unroll
        for (int ni = 0; ni < 4; ++ni) acc[mi][ni] = f32x4{0.f, 0.f, 0.f, 0.f};

    const short* Arow = wpb + (size_t)(m_base + l15) * 512 + 8 * g;
    const short* Brow = Ow + (size_t)(j_base + l15) * 512 + 8 * g;

    for (int ks = 0; ks < 16; ++ks) {
        s16x8 a[4], b[4];
#pragma unroll
        for (int i = 0; i < 4; ++i)
            a[i] = *(const s16x8*)(Arow + (size_t)i * 16 * 512 + ks * 32);
#pragma unroll
        for (int i = 0; i < 4; ++i)
            b[i] = *(const s16x8*)(Brow + (size_t)i * 16 * 512 + ks * 32);
#pragma unroll
        for (int mi = 0; mi < 4; ++mi)
#pragma unroll
            for (int ni = 0; ni < 4; ++ni)
                acc[mi][ni] = mfma16(a[mi], b[ni], acc[mi][ni]);
    }

#pragma unroll
    for (int mi = 0; mi < 4; ++mi) {
#pragma unroll
        for (int ni = 0; ni < 4; ++ni) {
            const int j = j_base + 16 * ni + l15;
            const int bb = j >> 10, n = j & 1023;
#pragma unroll
            for (int r = 0; r < 4; ++r) {
                const int c = m_base + 16 * mi + 4 * g + r;
                float v = acc[mi][ni][r] * s_p[c] + t_p[c];
                out[((size_t)bb * 384 + c) * 1024 + n] = v;
            }
        }
    }
}

extern "C" void kernel_launch(void* const* d_in, const int* in_sizes, int n_in,
                              void* d_out, int out_size, void* d_ws, size_t ws_size,
                              hipStream_t stream) {
    const float* x  = (const float*)d_in[0];
    const float* wq = (const float*)d_in[1];
    const float* gq = (const float*)d_in[2];
    const float* bq = (const float*)d_in[3];
    const float* mq = (const float*)d_in[4];
    const float* vq = (const float*)d_in[5];
    const float* wk = (const float*)d_in[6];
    const float* gk = (const float*)d_in[7];
    const float* bk = (const float*)d_in[8];
    const float* mk = (const float*)d_in[9];
    const float* vk = (const float*)d_in[10];
    const float* wv = (const float*)d_in[11];
    const float* gv = (const float*)d_in[12];
    const float* bv = (const float*)d_in[13];
    const float* mv = (const float*)d_in[14];
    const float* vv = (const float*)d_in[15];
    const float* wp = (const float*)d_in[16];
    const float* gp = (const float*)d_in[17];
    const float* bp = (const float*)d_in[18];
    const float* mp = (const float*)d_in[19];
    const float* vp = (const float*)d_in[20];
    float* out = (float*)d_out;

    char* ws = (char*)d_ws;
    size_t off = 0;
    auto alloc = [&](size_t bytes) {
        char* p = ws + off;
        off += (bytes + 255) & ~(size_t)255;
        return p;
    };
    short* xt    = (short*)alloc((size_t)8 * 1024 * 384 * 2);
    short* wqkv  = (short*)alloc((size_t)1024 * 384 * 2);
    short* wpb   = (short*)alloc((size_t)384 * 512 * 2);
    float* s_qkv = (float*)alloc(1024 * 4);
    float* t_qkv = (float*)alloc(1024 * 4);
    float* s_p   = (float*)alloc(384 * 4);
    float* t_p   = (float*)alloc(384 * 4);
    short* Qw    = (short*)alloc((size_t)8 * 8 * 1024 * 32 * 2);
    short* Kw    = (short*)alloc((size_t)8 * 8 * 1024 * 32 * 2);
    short* Vw    = (short*)alloc((size_t)8 * 8 * 64 * 1024 * 2);
    short* Ow    = (short*)alloc((size_t)8 * 1024 * 512 * 2);
    (void)ws_size; (void)in_sizes; (void)n_in; (void)out_size;

    k_prep_x<<<dim3(12, 32, 8), 256, 0, stream>>>(x, xt);
    k_prep_w<<<dim3((1024 * 384 + 384 * 512 + 255) / 256), 256, 0, stream>>>(
        wq, wk, wv, wp, wqkv, wpb);
    k_prep_bn<<<dim3(4), 256, 0, stream>>>(gq, bq, mq, vq, gk, bk, mk, vk,
                                           gv, bv, mv, vv, gp, bp, mp, vp,
                                           s_qkv, t_qkv, s_p, t_p);
    k_gemm_qkv<<<dim3(8, 64), 256, 0, stream>>>(wqkv, xt, s_qkv, t_qkv, Qw, Kw, Vw);
    k_attn<<<dim3(256), 256, 0, stream>>>(Qw, Kw, Vw, Ow);
    k_proj<<<dim3(3, 64), 256, 0, stream>>>(wpb, Ow, s_p, t_p, out);
}

// Round 2
// 117.762 us; speedup vs baseline: 1.0386x; 1.0386x over previous
//
#include <hip/hip_runtime.h>
#include <hip/hip_bf16.h>

#define DEVI __device__ __forceinline__

typedef __attribute__((ext_vector_type(8))) short s16x8;
typedef __attribute__((ext_vector_type(4))) short s16x4;
typedef __attribute__((ext_vector_type(4))) float f32x4;

// ---- problem constants ----
// x: (8, 384, 32, 32); heads=8, dk=32, dv=64; N=1024 tokens; Cqk=256, Cv=512

DEVI short f2bs(float f) {  // fp32 -> bf16 bits (RNE)
    unsigned u = __builtin_bit_cast(unsigned, f);
    unsigned r = (u + 0x7fffu + ((u >> 16) & 1u)) >> 16;
    return (short)r;
}

DEVI f32x4 mfma16(s16x8 a, s16x8 b, f32x4 c) {
    return __builtin_amdgcn_mfma_f32_16x16x32_bf16(a, b, c, 0, 0, 0);
}

// ---------------- prep: x (b,c,n) fp32 -> xt (b,n,c) bf16 ----------------
__global__ __launch_bounds__(256) void k_prep_x(const float* __restrict__ x,
                                                short* __restrict__ xt) {
    __shared__ float tile[32][33];
    const int ct = blockIdx.x, nt = blockIdx.y, b = blockIdx.z;
    const int t = threadIdx.x;
    {
        const int j = t & 31, i0 = (t >> 5) * 4;
        const float* src = x + ((size_t)b * 384 + (size_t)ct * 32) * 1024 + nt * 32;
#pragma unroll
        for (int ii = 0; ii < 4; ++ii)
            tile[i0 + ii][j] = src[(size_t)(i0 + ii) * 1024 + j];
    }
    __syncthreads();
    {
        const int ii = t & 31, j0 = (t >> 5) * 4;
        short* dst = xt + ((size_t)b * 1024 + (size_t)nt * 32) * 384 + ct * 32;
#pragma unroll
        for (int jj = 0; jj < 4; ++jj)
            dst[(size_t)(j0 + jj) * 384 + ii] = f2bs(tile[ii][j0 + jj]);
    }
}

// ---------------- prep: weights fp32 -> bf16, plus BN fold ----------------
__global__ __launch_bounds__(256) void k_prep_w(
    const float* __restrict__ wq, const float* __restrict__ wk,
    const float* __restrict__ wv, const float* __restrict__ wp,
    short* __restrict__ wqkv, short* __restrict__ wpb,
    const float* gq, const float* bq, const float* mq, const float* vq,
    const float* gk, const float* bk, const float* mk, const float* vk,
    const float* gv, const float* bv, const float* mv, const float* vv,
    const float* gp, const float* bp, const float* mp, const float* vp,
    float* s_qkv, float* t_qkv, float* s_p, float* t_p) {
    int i = blockIdx.x * 256 + threadIdx.x;
    if (i < 1024) {
        const float *g, *bb, *mm, *vv_;
        int o = i;
        if (i < 256)      { g = gq; bb = bq; mm = mq; vv_ = vq; }
        else if (i < 512) { g = gk; bb = bk; mm = mk; vv_ = vk; o = i - 256; }
        else              { g = gv; bb = bv; mm = mv; vv_ = vv; o = i - 512; }
        float s = g[o] * rsqrtf(vv_[o] + 1e-5f);
        s_qkv[i] = s;
        t_qkv[i] = bb[o] - mm[o] * s;
        if (i < 384) {
            float sp = gp[i] * rsqrtf(vp[i] + 1e-5f);
            s_p[i] = sp;
            t_p[i] = bp[i] - mp[i] * sp;
        }
    }
    const int NQKV = 1024 * 384;
    if (i < NQKV) {
        int o = i / 384;
        float v;
        if (o < 256)      v = wq[i];
        else if (o < 512) v = wk[i - 256 * 384];
        else              v = wv[i - 512 * 384];
        wqkv[i] = f2bs(v);
    } else {
        int j = i - NQKV;
        if (j < 384 * 512) wpb[j] = f2bs(wp[j]);
    }
}

// ---------------- QKV GEMM: [1024ch x 384] x [384 x 8192] + BN, layout-split ----------------
// Qw: [b][h][n][32]  Kw: [b][h][m][32]  Vw: [b][h][e][1024]
__global__ __launch_bounds__(256) void k_gemm_qkv(
    const short* __restrict__ wqkv, const short* __restrict__ xt,
    const float* __restrict__ s_qkv, const float* __restrict__ t_qkv,
    short* __restrict__ Qw, short* __restrict__ Kw, short* __restrict__ Vw) {
    const int t = threadIdx.x, lane = t & 63, w = t >> 6;
    const int g = lane >> 4, l15 = lane & 15;
    const int mb = blockIdx.x, jb = blockIdx.y;
    const int m_base = mb * 128 + (w >> 1) * 64;
    const int j_base = jb * 128 + (w & 1) * 64;

    f32x4 acc[4][4];
#pragma unroll
    for (int mi = 0; mi < 4; ++mi)
#pragma unroll
        for (int ni = 0; ni < 4; ++ni) acc[mi][ni] = f32x4{0.f, 0.f, 0.f, 0.f};

    const short* Arow = wqkv + (size_t)(m_base + l15) * 384 + 8 * g;
    const short* Brow = xt + (size_t)(j_base + l15) * 384 + 8 * g;

    for (int ks = 0; ks < 12; ++ks) {
        s16x8 a[4], b[4];
#pragma unroll
        for (int i = 0; i < 4; ++i)
            a[i] = *(const s16x8*)(Arow + (size_t)i * 16 * 384 + ks * 32);
#pragma unroll
        for (int i = 0; i < 4; ++i)
            b[i] = *(const s16x8*)(Brow + (size_t)i * 16 * 384 + ks * 32);
#pragma unroll
        for (int mi = 0; mi < 4; ++mi)
#pragma unroll
            for (int ni = 0; ni < 4; ++ni)
                acc[mi][ni] = mfma16(a[mi], b[ni], acc[mi][ni]);
    }

#pragma unroll
    for (int mi = 0; mi < 4; ++mi) {
        const int o0 = m_base + 16 * mi;
#pragma unroll
        for (int ni = 0; ni < 4; ++ni) {
            const int j = j_base + 16 * ni + l15;
            const int bb = j >> 10, n = j & 1023;
#pragma unroll
            for (int r = 0; r < 4; ++r) {
                const int o = o0 + 4 * g + r;
                float val = acc[mi][ni][r] * s_qkv[o] + t_qkv[o];
                short bv = f2bs(val);
                if (o0 < 256) {
                    int h = o >> 5, d = o & 31;
                    Qw[(((size_t)bb * 8 + h) * 1024 + n) * 32 + d] = bv;
                } else if (o0 < 512) {
                    int o2 = o - 256;
                    int h = o2 >> 5, d = o2 & 31;
                    Kw[(((size_t)bb * 8 + h) * 1024 + n) * 32 + d] = bv;
                } else {
                    int o2 = o - 512;
                    int h = o2 >> 6, e = o2 & 63;
                    Vw[(((size_t)bb * 8 + h) * 64 + e) * 1024 + n] = bv;
                }
            }
        }
    }
}

// ---------------- attention per (b,h): flash-online, S^T = mfma(K, Q) ----------------
// 32 q-rows per wave, 4 waves/block (128 rows), grid = 64 bh * 8 = 512 blocks
// Ow: [b][n][512] bf16, ReLU applied
__global__ __launch_bounds__(256) void k_attn(const short* __restrict__ Qw,
                                              const short* __restrict__ Kw,
                                              const short* __restrict__ Vw,
                                              short* __restrict__ Ow) {
    __shared__ short Plds[4][2048];  // per-wave 32x64 bf16, XOR-swizzled
    __shared__ float Srow[4][32];
    __shared__ float Lrow[4][32];
    const int t = threadIdx.x, lane = t & 63, w = t >> 6;
    const int g = lane >> 4, l15 = lane & 15;
    const int bh = blockIdx.x >> 3, rb = blockIdx.x & 7;
    const int n_base = rb * 128 + w * 32;
    const short* Qb = Qw + (size_t)bh * (1024 * 32);
    const short* Kb = Kw + (size_t)bh * (1024 * 32);
    const short* Vb = Vw + (size_t)bh * (64 * 1024);
    short* Pl = Plds[w];
    float* Sr = Srow[w];
    float* Lr = Lrow[w];

    s16x8 qf[2];
#pragma unroll
    for (int i = 0; i < 2; ++i)
        qf[i] = *(const s16x8*)(Qb + (size_t)(n_base + 16 * i + l15) * 32 + 8 * g);

    f32x4 oacc[2][4];
#pragma unroll
    for (int mi = 0; mi < 2; ++mi)
#pragma unroll
        for (int ei = 0; ei < 4; ++ei) oacc[mi][ei] = f32x4{0.f, 0.f, 0.f, 0.f};
    float m_run[2], l_run[2];
#pragma unroll
    for (int i = 0; i < 2; ++i) { m_run[i] = -3e38f; l_run[i] = 0.f; }

    for (int mt = 0; mt < 16; ++mt) {
        const int m0 = mt * 64;
        s16x8 kf[4];
#pragma unroll
        for (int i = 0; i < 4; ++i)
            kf[i] = *(const s16x8*)(Kb + (size_t)(m0 + 16 * i + l15) * 32 + 8 * g);

        f32x4 st[4][2];  // S^T: row m = m0+16*mik+4g+r, col n = n_base+16*niq+l15
#pragma unroll
        for (int mik = 0; mik < 4; ++mik)
#pragma unroll
            for (int niq = 0; niq < 2; ++niq)
                st[mik][niq] = mfma16(kf[mik], qf[niq], f32x4{0.f, 0.f, 0.f, 0.f});

        // per-column-n (softmax-row) stats: reduce over regs + lane-groups
        float mnew[2], sc[2];
#pragma unroll
        for (int niq = 0; niq < 2; ++niq) {
            float v = st[0][niq][0];
#pragma unroll
            for (int mik = 0; mik < 4; ++mik)
#pragma unroll
                for (int r = 0; r < 4; ++r) v = fmaxf(v, st[mik][niq][r]);
            v = fmaxf(v, __shfl_xor(v, 16, 64));
            v = fmaxf(v, __shfl_xor(v, 32, 64));
            mnew[niq] = fmaxf(m_run[niq], v);
            sc[niq] = __expf(m_run[niq] - mnew[niq]);
            m_run[niq] = mnew[niq];
        }
        float psum[2] = {0.f, 0.f};
#pragma unroll
        for (int mik = 0; mik < 4; ++mik)
#pragma unroll
            for (int niq = 0; niq < 2; ++niq)
#pragma unroll
                for (int r = 0; r < 4; ++r) {
                    float p = __expf(st[mik][niq][r] - mnew[niq]);
                    st[mik][niq][r] = p;
                    psum[niq] += p;
                }
#pragma unroll
        for (int niq = 0; niq < 2; ++niq) {
            float s = psum[niq];
            s += __shfl_xor(s, 16, 64);
            s += __shfl_xor(s, 32, 64);
            l_run[niq] = l_run[niq] * sc[niq] + s;
        }
        if (g == 0) {
#pragma unroll
            for (int niq = 0; niq < 2; ++niq) Sr[16 * niq + l15] = sc[niq];
        }
        // P (bf16) -> LDS, layout P[n_local][m_local], byte ^= (n&7)<<4
#pragma unroll
        for (int mik = 0; mik < 4; ++mik)
#pragma unroll
            for (int niq = 0; niq < 2; ++niq) {
                s16x4 pk;
#pragma unroll
                for (int r = 0; r < 4; ++r) pk[r] = f2bs(st[mik][niq][r]);
                const int nr = 16 * niq + l15;
                const int off = (nr * 128 + 32 * mik + 8 * g) ^ ((nr & 7) << 4);
                *(s16x4*)((char*)Pl + off) = pk;
            }
        // rescale O by sc of its rows (rows n = 16*mi + 4g + r here)
        {
            float sco[2][4];
#pragma unroll
            for (int mi = 0; mi < 2; ++mi)
#pragma unroll
                for (int r = 0; r < 4; ++r) sco[mi][r] = Sr[16 * mi + 4 * g + r];
#pragma unroll
            for (int mi = 0; mi < 2; ++mi)
#pragma unroll
                for (int ei = 0; ei < 4; ++ei)
#pragma unroll
                    for (int r = 0; r < 4; ++r) oacc[mi][ei][r] *= sco[mi][r];
        }
        // PV: out[n][e] += P[n][m] * V[m][e]
#pragma unroll
        for (int ki = 0; ki < 2; ++ki) {
            s16x8 pa[2];
#pragma unroll
            for (int mi = 0; mi < 2; ++mi) {
                const int nr = 16 * mi + l15;
                const int off = (nr * 128 + 64 * ki + 16 * g) ^ ((nr & 7) << 4);
                pa[mi] = *(const s16x8*)((char*)Pl + off);
            }
            s16x8 vb[4];
#pragma unroll
            for (int ei = 0; ei < 4; ++ei)
                vb[ei] = *(const s16x8*)(Vb + (size_t)(16 * ei + l15) * 1024 + m0 + 32 * ki + 8 * g);
#pragma unroll
            for (int mi = 0; mi < 2; ++mi)
#pragma unroll
                for (int ei = 0; ei < 4; ++ei)
                    oacc[mi][ei] = mfma16(pa[mi], vb[ei], oacc[mi][ei]);
        }
    }

    if (g == 0) {
#pragma unroll
        for (int niq = 0; niq < 2; ++niq) Lr[16 * niq + l15] = l_run[niq];
    }
    const int b = bh >> 3, h = bh & 7;
#pragma unroll
    for (int mi = 0; mi < 2; ++mi) {
        float li[4];
#pragma unroll
        for (int r = 0; r < 4; ++r) li[r] = 1.0f / Lr[16 * mi + 4 * g + r];
#pragma unroll
        for (int ei = 0; ei < 4; ++ei) {
            const int e = 16 * ei + l15;
#pragma unroll
            for (int r = 0; r < 4; ++r) {
                const int n = n_base + 16 * mi + 4 * g + r;
                float v = fmaxf(oacc[mi][ei][r] * li[r], 0.f);
                Ow[((size_t)b * 1024 + n) * 512 + h * 64 + e] = f2bs(v);
            }
        }
    }
}

// ---------------- proj GEMM: [384 x 512] x [512 x 8192] + BN -> fp32 out ----------------
__global__ __launch_bounds__(256) void k_proj(const short* __restrict__ wpb,
                                              const short* __restrict__ Ow,
                                              const float* __restrict__ s_p,
                                              const float* __restrict__ t_p,
                                              float* __restrict__ out) {
    const int t = threadIdx.x, lane = t & 63, w = t >> 6;
    const int g = lane >> 4, l15 = lane & 15;
    const int mb = blockIdx.x, jb = blockIdx.y;
    const int m_base = mb * 128 + (w >> 1) * 64;
    const int j_base = jb * 128 + (w & 1) * 64;

    f32x4 acc[4][4];
#pragma unroll
    for (int mi = 0; mi < 4; ++mi)
#pragma unroll
        for (int ni = 0; ni < 4; ++ni) acc[mi][ni] = f32x4{0.f, 0.f, 0.f, 0.f};

    const short* Arow = wpb + (size_t)(m_base + l15) * 512 + 8 * g;
    const short* Brow = Ow + (size_t)(j_base + l15) * 512 + 8 * g;

    for (int ks = 0; ks < 16; ++ks) {
        s16x8 a[4], b[4];
#pragma unroll
        for (int i = 0; i < 4; ++i)
            a[i] = *(const s16x8*)(Arow + (size_t)i * 16 * 512 + ks * 32);
#pragma unroll
        for (int i = 0; i < 4; ++i)
            b[i] = *(const s16x8*)(Brow + (size_t)i * 16 * 512 + ks * 32);
#pragma unroll
        for (int mi = 0; mi < 4; ++mi)
#pragma unroll
            for (int ni = 0; ni < 4; ++ni)
                acc[mi][ni] = mfma16(a[mi], b[ni], acc[mi][ni]);
    }

#pragma unroll
    for (int mi = 0; mi < 4; ++mi) {
#pragma unroll
        for (int ni = 0; ni < 4; ++ni) {
            const int j = j_base + 16 * ni + l15;
            const int bb = j >> 10, n = j & 1023;
#pragma unroll
            for (int r = 0; r < 4; ++r) {
                const int c = m_base + 16 * mi + 4 * g + r;
                float v = acc[mi][ni][r] * s_p[c] + t_p[c];
                out[((size_t)bb * 384 + c) * 1024 + n] = v;
            }
        }
    }
}

extern "C" void kernel_launch(void* const* d_in, const int* in_sizes, int n_in,
                              void* d_out, int out_size, void* d_ws, size_t ws_size,
                              hipStream_t stream) {
    const float* x  = (const float*)d_in[0];
    const float* wq = (const float*)d_in[1];
    const float* gq = (const float*)d_in[2];
    const float* bq = (const float*)d_in[3];
    const float* mq = (const float*)d_in[4];
    const float* vq = (const float*)d_in[5];
    const float* wk = (const float*)d_in[6];
    const float* gk = (const float*)d_in[7];
    const float* bk = (const float*)d_in[8];
    const float* mk = (const float*)d_in[9];
    const float* vk = (const float*)d_in[10];
    const float* wv = (const float*)d_in[11];
    const float* gv = (const float*)d_in[12];
    const float* bv = (const float*)d_in[13];
    const float* mv = (const float*)d_in[14];
    const float* vv = (const float*)d_in[15];
    const float* wp = (const float*)d_in[16];
    const float* gp = (const float*)d_in[17];
    const float* bp = (const float*)d_in[18];
    const float* mp = (const float*)d_in[19];
    const float* vp = (const float*)d_in[20];
    float* out = (float*)d_out;

    char* ws = (char*)d_ws;
    size_t off = 0;
    auto alloc = [&](size_t bytes) {
        char* p = ws + off;
        off += (bytes + 255) & ~(size_t)255;
        return p;
    };
    short* xt    = (short*)alloc((size_t)8 * 1024 * 384 * 2);
    short* wqkv  = (short*)alloc((size_t)1024 * 384 * 2);
    short* wpb   = (short*)alloc((size_t)384 * 512 * 2);
    float* s_qkv = (float*)alloc(1024 * 4);
    float* t_qkv = (float*)alloc(1024 * 4);
    float* s_p   = (float*)alloc(384 * 4);
    float* t_p   = (float*)alloc(384 * 4);
    short* Qw    = (short*)alloc((size_t)8 * 8 * 1024 * 32 * 2);
    short* Kw    = (short*)alloc((size_t)8 * 8 * 1024 * 32 * 2);
    short* Vw    = (short*)alloc((size_t)8 * 8 * 64 * 1024 * 2);
    short* Ow    = (short*)alloc((size_t)8 * 1024 * 512 * 2);
    (void)ws_size; (void)in_sizes; (void)n_in; (void)out_size;

    k_prep_x<<<dim3(12, 32, 8), 256, 0, stream>>>(x, xt);
    k_prep_w<<<dim3((1024 * 384 + 384 * 512 + 255) / 256), 256, 0, stream>>>(
        wq, wk, wv, wp, wqkv, wpb,
        gq, bq, mq, vq, gk, bk, mk, vk, gv, bv, mv, vv, gp, bp, mp, vp,
        s_qkv, t_qkv, s_p, t_p);
    k_gemm_qkv<<<dim3(8, 64), 256, 0, stream>>>(wqkv, xt, s_qkv, t_qkv, Qw, Kw, Vw);
    k_attn<<<dim3(512), 256, 0, stream>>>(Qw, Kw, Vw, Ow);
    k_proj<<<dim3(3, 64), 256, 0, stream>>>(wpb, Ow, s_p, t_p, out);
}

// Round 3
// 112.482 us; speedup vs baseline: 1.0874x; 1.0469x over previous
//
#include <hip/hip_runtime.h>
#include <hip/hip_bf16.h>

#define DEVI __device__ __forceinline__

typedef __attribute__((ext_vector_type(8))) short s16x8;
typedef __attribute__((ext_vector_type(4))) short s16x4;
typedef __attribute__((ext_vector_type(4))) float f32x4;

// ---- problem constants ----
// x: (8, 384, 32, 32); heads=8, dk=32, dv=64; N=1024 tokens; Cqk=256, Cv=512
#define LOG2E 1.4426950408889634f

DEVI short f2bs(float f) {  // fp32 -> bf16 bits (RNE)
    unsigned u = __builtin_bit_cast(unsigned, f);
    unsigned r = (u + 0x7fffu + ((u >> 16) & 1u)) >> 16;
    return (short)r;
}

DEVI f32x4 mfma16(s16x8 a, s16x8 b, f32x4 c) {
    return __builtin_amdgcn_mfma_f32_16x16x32_bf16(a, b, c, 0, 0, 0);
}

// ---------------- prep: x (b,c,n) fp32 -> xt (b,n,c) bf16 ----------------
__global__ __launch_bounds__(256) void k_prep_x(const float* __restrict__ x,
                                                short* __restrict__ xt) {
    __shared__ float tile[32][33];
    const int ct = blockIdx.x, nt = blockIdx.y, b = blockIdx.z;
    const int t = threadIdx.x;
    {
        const int j = t & 31, i0 = (t >> 5) * 4;
        const float* src = x + ((size_t)b * 384 + (size_t)ct * 32) * 1024 + nt * 32;
#pragma unroll
        for (int ii = 0; ii < 4; ++ii)
            tile[i0 + ii][j] = src[(size_t)(i0 + ii) * 1024 + j];
    }
    __syncthreads();
    {
        const int ii = t & 31, j0 = (t >> 5) * 4;
        short* dst = xt + ((size_t)b * 1024 + (size_t)nt * 32) * 384 + ct * 32;
#pragma unroll
        for (int jj = 0; jj < 4; ++jj)
            dst[(size_t)(j0 + jj) * 384 + ii] = f2bs(tile[ii][j0 + jj]);
    }
}

// ---------------- prep: weights fp32 -> bf16, plus BN fold ----------------
// Q-channel BN scale/shift are folded with LOG2E so softmax exp becomes exp2.
__global__ __launch_bounds__(256) void k_prep_w(
    const float* __restrict__ wq, const float* __restrict__ wk,
    const float* __restrict__ wv, const float* __restrict__ wp,
    short* __restrict__ wqkv, short* __restrict__ wpb,
    const float* gq, const float* bq, const float* mq, const float* vq,
    const float* gk, const float* bk, const float* mk, const float* vk,
    const float* gv, const float* bv, const float* mv, const float* vv,
    const float* gp, const float* bp, const float* mp, const float* vp,
    float* s_qkv, float* t_qkv, float* s_p, float* t_p) {
    int i = blockIdx.x * 256 + threadIdx.x;
    if (i < 1024) {
        const float *g, *bb, *mm, *vv_;
        int o = i;
        float post = 1.0f;
        if (i < 256)      { g = gq; bb = bq; mm = mq; vv_ = vq; post = LOG2E; }
        else if (i < 512) { g = gk; bb = bk; mm = mk; vv_ = vk; o = i - 256; }
        else              { g = gv; bb = bv; mm = mv; vv_ = vv; o = i - 512; }
        float s = g[o] * rsqrtf(vv_[o] + 1e-5f);
        s_qkv[i] = s * post;
        t_qkv[i] = (bb[o] - mm[o] * s) * post;
        if (i < 384) {
            float sp = gp[i] * rsqrtf(vp[i] + 1e-5f);
            s_p[i] = sp;
            t_p[i] = bp[i] - mp[i] * sp;
        }
    }
    const int NQKV = 1024 * 384;
    if (i < NQKV) {
        int o = i / 384;
        float v;
        if (o < 256)      v = wq[i];
        else if (o < 512) v = wk[i - 256 * 384];
        else              v = wv[i - 512 * 384];
        wqkv[i] = f2bs(v);
    } else {
        int j = i - NQKV;
        if (j < 384 * 512) wpb[j] = f2bs(wp[j]);
    }
}

// ---------------- QKV GEMM: [1024ch x 384] x [384 x 8192] + BN, layout-split ----------------
// Qw: [b][h][n][32]  Kw: [b][h][m][32]  Vw: [b][h][e][1024]
__global__ __launch_bounds__(256) void k_gemm_qkv(
    const short* __restrict__ wqkv, const short* __restrict__ xt,
    const float* __restrict__ s_qkv, const float* __restrict__ t_qkv,
    short* __restrict__ Qw, short* __restrict__ Kw, short* __restrict__ Vw) {
    const int t = threadIdx.x, lane = t & 63, w = t >> 6;
    const int g = lane >> 4, l15 = lane & 15;
    const int mb = blockIdx.x, jb = blockIdx.y;
    const int m_base = mb * 128 + (w >> 1) * 64;
    const int j_base = jb * 128 + (w & 1) * 64;

    f32x4 acc[4][4];
#pragma unroll
    for (int mi = 0; mi < 4; ++mi)
#pragma unroll
        for (int ni = 0; ni < 4; ++ni) acc[mi][ni] = f32x4{0.f, 0.f, 0.f, 0.f};

    const short* Arow = wqkv + (size_t)(m_base + l15) * 384 + 8 * g;
    const short* Brow = xt + (size_t)(j_base + l15) * 384 + 8 * g;

    for (int ks = 0; ks < 12; ++ks) {
        s16x8 a[4], b[4];
#pragma unroll
        for (int i = 0; i < 4; ++i)
            a[i] = *(const s16x8*)(Arow + (size_t)i * 16 * 384 + ks * 32);
#pragma unroll
        for (int i = 0; i < 4; ++i)
            b[i] = *(const s16x8*)(Brow + (size_t)i * 16 * 384 + ks * 32);
#pragma unroll
        for (int mi = 0; mi < 4; ++mi)
#pragma unroll
            for (int ni = 0; ni < 4; ++ni)
                acc[mi][ni] = mfma16(a[mi], b[ni], acc[mi][ni]);
    }

#pragma unroll
    for (int mi = 0; mi < 4; ++mi) {
        const int o0 = m_base + 16 * mi;
#pragma unroll
        for (int ni = 0; ni < 4; ++ni) {
            const int j = j_base + 16 * ni + l15;
            const int bb = j >> 10, n = j & 1023;
#pragma unroll
            for (int r = 0; r < 4; ++r) {
                const int o = o0 + 4 * g + r;
                float val = acc[mi][ni][r] * s_qkv[o] + t_qkv[o];
                short bv = f2bs(val);
                if (o0 < 256) {
                    int h = o >> 5, d = o & 31;
                    Qw[(((size_t)bb * 8 + h) * 1024 + n) * 32 + d] = bv;
                } else if (o0 < 512) {
                    int o2 = o - 256;
                    int h = o2 >> 5, d = o2 & 31;
                    Kw[(((size_t)bb * 8 + h) * 1024 + n) * 32 + d] = bv;
                } else {
                    int o2 = o - 512;
                    int h = o2 >> 6, e = o2 & 63;
                    Vw[(((size_t)bb * 8 + h) * 64 + e) * 1024 + n] = bv;
                }
            }
        }
    }
}

// ---------------- attention per (b,h): no-max softmax (S bounded), S^T = mfma(K, Q) ----------------
// 32 q-rows per wave, 4 waves/block; grid = 64 bh * 8 rb = 512 blocks, XCD-grouped.
// P = exp2(S') with S' = log2e*S folded into Q. Iterations independent -> pipelined.
// Ow: [b][n][512] bf16, ReLU applied
__global__ __launch_bounds__(256) void k_attn(const short* __restrict__ Qw,
                                              const short* __restrict__ Kw,
                                              const short* __restrict__ Vw,
                                              short* __restrict__ Ow) {
    __shared__ short Plds[4][2][2048];  // per-wave double-buffered 32x64 bf16, XOR-swizzled
    __shared__ float Lrow[4][32];
    const int t = threadIdx.x, lane = t & 63, w = t >> 6;
    const int g = lane >> 4, l15 = lane & 15;
    // blockIdx.x = (bh&7) + 8*((bh>>3)*8 + rb)  => all rb of a bh share an XCD
    const int low3 = blockIdx.x & 7;
    const int mid = blockIdx.x >> 3;
    const int rb = mid & 7;
    const int bh = ((mid >> 3) << 3) | low3;
    const int n_base = rb * 128 + w * 32;
    const short* Qb = Qw + (size_t)bh * (1024 * 32);
    const short* Kb = Kw + (size_t)bh * (1024 * 32);
    const short* Vb = Vw + (size_t)bh * (64 * 1024);
    float* Lr = Lrow[w];

    s16x8 qf[2];
#pragma unroll
    for (int i = 0; i < 2; ++i)
        qf[i] = *(const s16x8*)(Qb + (size_t)(n_base + 16 * i + l15) * 32 + 8 * g);

    f32x4 oacc[2][4];
#pragma unroll
    for (int mi = 0; mi < 2; ++mi)
#pragma unroll
        for (int ei = 0; ei < 4; ++ei) oacc[mi][ei] = f32x4{0.f, 0.f, 0.f, 0.f};
    float l_part[2] = {0.f, 0.f};

    s16x8 kf[4];
#pragma unroll
    for (int i = 0; i < 4; ++i)
        kf[i] = *(const s16x8*)(Kb + (size_t)(16 * i + l15) * 32 + 8 * g);

    for (int mt = 0; mt < 16; ++mt) {
        const int m0 = mt * 64;
        // QK^T (S^T: row m = m0+16*mik+4g+r, col n = n_base+16*niq+l15)
        __builtin_amdgcn_s_setprio(1);
        f32x4 st[4][2];
#pragma unroll
        for (int mik = 0; mik < 4; ++mik)
#pragma unroll
            for (int niq = 0; niq < 2; ++niq)
                st[mik][niq] = mfma16(kf[mik], qf[niq], f32x4{0.f, 0.f, 0.f, 0.f});
        __builtin_amdgcn_s_setprio(0);

        // prefetch next K tile (overlaps exp/pack below)
        if (mt < 15) {
#pragma unroll
            for (int i = 0; i < 4; ++i)
                kf[i] = *(const s16x8*)(Kb + (size_t)(m0 + 64 + 16 * i + l15) * 32 + 8 * g);
        }
        // prefetch V for this tile
        s16x8 vb[2][4];
#pragma unroll
        for (int ki = 0; ki < 2; ++ki)
#pragma unroll
            for (int ei = 0; ei < 4; ++ei)
                vb[ki][ei] = *(const s16x8*)(Vb + (size_t)(16 * ei + l15) * 1024 + m0 + 32 * ki + 8 * g);

        // P = exp2(S'), accumulate per-lane l partials, pack bf16 -> LDS (parity buffer)
        short* Pl = Plds[w][mt & 1];
#pragma unroll
        for (int mik = 0; mik < 4; ++mik)
#pragma unroll
            for (int niq = 0; niq < 2; ++niq) {
                float p[4];
#pragma unroll
                for (int r = 0; r < 4; ++r) p[r] = __builtin_amdgcn_exp2f(st[mik][niq][r]);
                l_part[niq] += (p[0] + p[1]) + (p[2] + p[3]);
                s16x4 pk;
#pragma unroll
                for (int r = 0; r < 4; ++r)
                    pk[r] = __builtin_bit_cast(short, __float2bfloat16(p[r]));
                const int nr = 16 * niq + l15;
                const int off = (nr * 128 + 32 * mik + 8 * g) ^ ((nr & 7) << 4);
                *(s16x4*)((char*)Pl + off) = pk;
            }

        // PV: out[n][e] += P[n][m] * V[m][e]
#pragma unroll
        for (int ki = 0; ki < 2; ++ki) {
            s16x8 pa[2];
#pragma unroll
            for (int mi = 0; mi < 2; ++mi) {
                const int nr = 16 * mi + l15;
                const int off = (nr * 128 + 64 * ki + 16 * g) ^ ((nr & 7) << 4);
                pa[mi] = *(const s16x8*)((char*)Pl + off);
            }
            __builtin_amdgcn_s_setprio(1);
#pragma unroll
            for (int mi = 0; mi < 2; ++mi)
#pragma unroll
                for (int ei = 0; ei < 4; ++ei)
                    oacc[mi][ei] = mfma16(pa[mi], vb[ki][ei], oacc[mi][ei]);
            __builtin_amdgcn_s_setprio(0);
        }
    }

    // final l reduction across g groups (deferred out of the loop)
#pragma unroll
    for (int niq = 0; niq < 2; ++niq) {
        float s = l_part[niq];
        s += __shfl_xor(s, 16, 64);
        s += __shfl_xor(s, 32, 64);
        if (g == 0) Lr[16 * niq + l15] = s;
    }
    const int b = bh >> 3, h = bh & 7;
#pragma unroll
    for (int mi = 0; mi < 2; ++mi) {
        float li[4];
#pragma unroll
        for (int r = 0; r < 4; ++r) li[r] = __builtin_amdgcn_rcpf(Lr[16 * mi + 4 * g + r]);
#pragma unroll
        for (int ei = 0; ei < 4; ++ei) {
            const int e = 16 * ei + l15;
#pragma unroll
            for (int r = 0; r < 4; ++r) {
                const int n = n_base + 16 * mi + 4 * g + r;
                float v = fmaxf(oacc[mi][ei][r] * li[r], 0.f);
                Ow[((size_t)b * 1024 + n) * 512 + h * 64 + e] = f2bs(v);
            }
        }
    }
}

// ---------------- proj GEMM: [384 x 512] x [512 x 8192] + BN -> fp32 out ----------------
__global__ __launch_bounds__(256) void k_proj(const short* __restrict__ wpb,
                                              const short* __restrict__ Ow,
                                              const float* __restrict__ s_p,
                                              const float* __restrict__ t_p,
                                              float* __restrict__ out) {
    const int t = threadIdx.x, lane = t & 63, w = t >> 6;
    const int g = lane >> 4, l15 = lane & 15;
    const int mb = blockIdx.x, jb = blockIdx.y;
    const int m_base = mb * 128 + (w >> 1) * 64;
    const int j_base = jb * 128 + (w & 1) * 64;

    f32x4 acc[4][4];
#pragma unroll
    for (int mi = 0; mi < 4; ++mi)
#pragma unroll
        for (int ni = 0; ni < 4; ++ni) acc[mi][ni] = f32x4{0.f, 0.f, 0.f, 0.f};

    const short* Arow = wpb + (size_t)(m_base + l15) * 512 + 8 * g;
    const short* Brow = Ow + (size_t)(j_base + l15) * 512 + 8 * g;

    for (int ks = 0; ks < 16; ++ks) {
        s16x8 a[4], b[4];
#pragma unroll
        for (int i = 0; i < 4; ++i)
            a[i] = *(const s16x8*)(Arow + (size_t)i * 16 * 512 + ks * 32);
#pragma unroll
        for (int i = 0; i < 4; ++i)
            b[i] = *(const s16x8*)(Brow + (size_t)i * 16 * 512 + ks * 32);
#pragma unroll
        for (int mi = 0; mi < 4; ++mi)
#pragma unroll
            for (int ni = 0; ni < 4; ++ni)
                acc[mi][ni] = mfma16(a[mi], b[ni], acc[mi][ni]);
    }

#pragma unroll
    for (int mi = 0; mi < 4; ++mi) {
#pragma unroll
        for (int ni = 0; ni < 4; ++ni) {
            const int j = j_base + 16 * ni + l15;
            const int bb = j >> 10, n = j & 1023;
#pragma unroll
            for (int r = 0; r < 4; ++r) {
                const int c = m_base + 16 * mi + 4 * g + r;
                float v = acc[mi][ni][r] * s_p[c] + t_p[c];
                out[((size_t)bb * 384 + c) * 1024 + n] = v;
            }
        }
    }
}

extern "C" void kernel_launch(void* const* d_in, const int* in_sizes, int n_in,
                              void* d_out, int out_size, void* d_ws, size_t ws_size,
                              hipStream_t stream) {
    const float* x  = (const float*)d_in[0];
    const float* wq = (const float*)d_in[1];
    const float* gq = (const float*)d_in[2];
    const float* bq = (const float*)d_in[3];
    const float* mq = (const float*)d_in[4];
    const float* vq = (const float*)d_in[5];
    const float* wk = (const float*)d_in[6];
    const float* gk = (const float*)d_in[7];
    const float* bk = (const float*)d_in[8];
    const float* mk = (const float*)d_in[9];
    const float* vk = (const float*)d_in[10];
    const float* wv = (const float*)d_in[11];
    const float* gv = (const float*)d_in[12];
    const float* bv = (const float*)d_in[13];
    const float* mv = (const float*)d_in[14];
    const float* vv = (const float*)d_in[15];
    const float* wp = (const float*)d_in[16];
    const float* gp = (const float*)d_in[17];
    const float* bp = (const float*)d_in[18];
    const float* mp = (const float*)d_in[19];
    const float* vp = (const float*)d_in[20];
    float* out = (float*)d_out;

    char* ws = (char*)d_ws;
    size_t off = 0;
    auto alloc = [&](size_t bytes) {
        char* p = ws + off;
        off += (bytes + 255) & ~(size_t)255;
        return p;
    };
    short* xt    = (short*)alloc((size_t)8 * 1024 * 384 * 2);
    short* wqkv  = (short*)alloc((size_t)1024 * 384 * 2);
    short* wpb   = (short*)alloc((size_t)384 * 512 * 2);
    float* s_qkv = (float*)alloc(1024 * 4);
    float* t_qkv = (float*)alloc(1024 * 4);
    float* s_p   = (float*)alloc(384 * 4);
    float* t_p   = (float*)alloc(384 * 4);
    short* Qw    = (short*)alloc((size_t)8 * 8 * 1024 * 32 * 2);
    short* Kw    = (short*)alloc((size_t)8 * 8 * 1024 * 32 * 2);
    short* Vw    = (short*)alloc((size_t)8 * 8 * 64 * 1024 * 2);
    short* Ow    = (short*)alloc((size_t)8 * 1024 * 512 * 2);
    (void)ws_size; (void)in_sizes; (void)n_in; (void)out_size;

    k_prep_x<<<dim3(12, 32, 8), 256, 0, stream>>>(x, xt);
    k_prep_w<<<dim3((1024 * 384 + 384 * 512 + 255) / 256), 256, 0, stream>>>(
        wq, wk, wv, wp, wqkv, wpb,
        gq, bq, mq, vq, gk, bk, mk, vk, gv, bv, mv, vv, gp, bp, mp, vp,
        s_qkv, t_qkv, s_p, t_p);
    k_gemm_qkv<<<dim3(8, 64), 256, 0, stream>>>(wqkv, xt, s_qkv, t_qkv, Qw, Kw, Vw);
    k_attn<<<dim3(512), 256, 0, stream>>>(Qw, Kw, Vw, Ow);
    k_proj<<<dim3(3, 64), 256, 0, stream>>>(wpb, Ow, s_p, t_p, out);
}